// Round 1
// baseline (98.072 us; speedup 1.0000x reference)
//
#include <hip/hip_runtime.h>
#include <float.h>

#define OUT 7

// One thread per output element.
// Output layout: [R, C, 7, 7] flat contiguous -> out[idx] with
// idx = ((r*C + c)*7 + oh)*7 + ow. Consecutive threads write consecutive
// addresses => fully coalesced stores (the write stream dominates: ~103 MB).
__global__ __launch_bounds__(256) void roi_pool_kernel(
    const float* __restrict__ features,   // [C, H, W] (batch 1)
    const int4*  __restrict__ rois,       // [R] of (x1,y1,x2,y2) image-pixel coords
    float* __restrict__ out,              // [R, C, 7, 7]
    int total, int C, int H, int W)
{
    int idx = blockIdx.x * blockDim.x + threadIdx.x;
    if (idx >= total) return;

    int ow = idx % OUT;
    int t  = idx / OUT;
    int oh = t % OUT;
    t /= OUT;                 // t = r*C + c
    int c = t & (512 - 1);    // C == 512
    int r = t >> 9;

    int4 roi = rois[r];
    // (x * 1.0f/16.0f) truncated to int == x >> 4 for x in [0, 1024): exact fp32.
    int x1 = roi.x >> 4;
    int y1 = roi.y >> 4;
    int x2 = roi.z >> 4;
    int y2 = roi.w >> 4;

    int h_len = y2 - y1 + 1;
    int w_len = x2 - x1 + 1;

    // torch adaptive bins: [floor(i*L/OUT), ceil((i+1)*L/OUT))
    int hs = y1 + (oh * h_len) / OUT;
    int he = y1 + ((oh + 1) * h_len + (OUT - 1)) / OUT;
    int ws = x1 + (ow * w_len) / OUT;
    int we = x1 + ((ow + 1) * w_len + (OUT - 1)) / OUT;

    // Clamp to grid (reference masks clip to [0, H)/[0, W); inputs are in
    // bounds by construction but this is free insurance).
    if (hs < 0) hs = 0;
    if (ws < 0) ws = 0;
    if (he > H) he = H;
    if (we > W) we = W;

    const float* fc = features + (size_t)c * H * W;
    float m = -FLT_MAX;
    for (int h = hs; h < he; ++h) {
        const float* row = fc + h * W;
        for (int w = ws; w < we; ++w) {
            float v = row[w];
            m = v > m ? v : m;
        }
    }
    out[idx] = m;
}

extern "C" void kernel_launch(void* const* d_in, const int* in_sizes, int n_in,
                              void* d_out, int out_size, void* d_ws, size_t ws_size,
                              hipStream_t stream) {
    const float* features = (const float*)d_in[0];   // [1,512,64,64] fp32
    const int4*  rois     = (const int4*)d_in[1];    // [R,4] int32
    float* out = (float*)d_out;

    const int C = 512, H = 64, W = 64;
    int total = out_size;                            // R*C*7*7

    int threads = 256;
    int blocks = (total + threads - 1) / threads;
    roi_pool_kernel<<<blocks, threads, 0, stream>>>(features, rois, out, total, C, H, W);
}